// Round 4
// baseline (26.533 us; speedup 1.0000x reference)
//
#include <hip/hip_runtime.h>
#include <math.h>

#define NB 16384

// Batch-independent constants staged in LDS (uniform broadcast reads).
struct SConsts {
  float MrT[8][9];  // transpose of Mlist[i][:3,:3], row-major
  float mp[8][3];   // Mlist[i][:3,3]
  float A[7][6];    // screw axes
  float Gd[7][6];   // [Ixx,Iyy,Izz,m,m,m]
  float X7p[3];     // p of adjoint(trans_inv(Mlist[7])); its R is MrT[7]
  float g[3];
  float ftip[6];
};

// Block = 64 threads = ONE wave. LDS ops from a single wave are processed
// in order by the LDS unit, so cross-lane ds_write -> ds_read needs no
// s_barrier and no lgkmcnt(0) drain. This fence is compile-time only: it
// stops the scheduler from reordering DS ops across the logical sync point.
__device__ __forceinline__ void syncw() {
  __builtin_amdgcn_sched_barrier(0);
  __builtin_amdgcn_wave_barrier();
  __builtin_amdgcn_sched_barrier(0);
}

__device__ __forceinline__ float dot6(const float* a, const float* b) {
  return a[0]*b[0]+a[1]*b[1]+a[2]*b[2]+a[3]*b[3]+a[4]*b[4]+a[5]*b[5];
}

// exp6 with native sin/cos/sqrt/rcp (1-2 ulp; threshold 0.4 >> effect).
__device__ __forceinline__ void exp6_dev(float wx, float wy, float wz,
                                         float vx, float vy, float vz,
                                         float R[9], float p[3]) {
  float th2 = wx*wx + wy*wy + wz*wz;
  float th  = __builtin_amdgcn_sqrtf(th2);
  bool sm = th < 1e-10f;
  float ths = sm ? 1.0f : th;
  float inv = __builtin_amdgcn_rcpf(ths);
  float ux = wx*inv, uy = wy*inv, uz = wz*inv;
  float s = __sinf(th);
  float c = __cosf(th);
  float omc = 1.0f - c;
  float r00 = c + omc*ux*ux;
  float r01 = omc*ux*uy - s*uz;
  float r02 = omc*ux*uz + s*uy;
  float r10 = omc*uy*ux + s*uz;
  float r11 = c + omc*uy*uy;
  float r12 = omc*uy*uz - s*ux;
  float r20 = omc*uz*ux - s*uy;
  float r21 = omc*uz*uy + s*ux;
  float r22 = c + omc*uz*uz;
  float k1 = omc*inv, k2 = (th - s)*inv;
  float cx = uy*vz - uz*vy, cy = uz*vx - ux*vz, cz = ux*vy - uy*vx;
  float udv = ux*vx + uy*vy + uz*vz;
  float px = vx + k1*cx + k2*(ux*udv - vx);
  float py = vy + k1*cy + k2*(uy*udv - vy);
  float pz = vz + k1*cz + k2*(uz*udv - vz);
  R[0]=sm?1.f:r00; R[1]=sm?0.f:r01; R[2]=sm?0.f:r02;
  R[3]=sm?0.f:r10; R[4]=sm?1.f:r11; R[5]=sm?0.f:r12;
  R[6]=sm?0.f:r20; R[7]=sm?0.f:r21; R[8]=sm?1.f:r22;
  p[0]=sm?vx:px; p[1]=sm?vy:py; p[2]=sm?vz:pz;
}

// Adjoint apply: out = Ad(R,p) * in, in = (w,v). top = Rw; bot = p x (Rw) + Rv.
__device__ __forceinline__ void Xapply(const float* R, const float* p,
                                       const float in[6], float out[6]) {
  float a = R[0]*in[0]+R[1]*in[1]+R[2]*in[2];
  float b = R[3]*in[0]+R[4]*in[1]+R[5]*in[2];
  float c = R[6]*in[0]+R[7]*in[1]+R[8]*in[2];
  float d = R[0]*in[3]+R[1]*in[4]+R[2]*in[5];
  float e = R[3]*in[3]+R[4]*in[4]+R[5]*in[5];
  float f = R[6]*in[3]+R[7]*in[4]+R[8]*in[5];
  out[0]=a; out[1]=b; out[2]=c;
  out[3] = p[1]*c - p[2]*b + d;
  out[4] = p[2]*a - p[0]*c + e;
  out[5] = p[0]*b - p[1]*a + f;
}

// Adjoint-transpose apply: in = (m,f). top = R^T (m - p x f); bot = R^T f.
__device__ __forceinline__ void XTapply(const float* R, const float* p,
                                        const float in[6], float out[6]) {
  float fx=in[3], fy=in[4], fz=in[5];
  float tx = in[0] - (p[1]*fz - p[2]*fy);
  float ty = in[1] - (p[2]*fx - p[0]*fz);
  float tz = in[2] - (p[0]*fy - p[1]*fx);
  out[0] = R[0]*tx + R[3]*ty + R[6]*tz;
  out[1] = R[1]*tx + R[4]*ty + R[7]*tz;
  out[2] = R[2]*tx + R[5]*ty + R[8]*tz;
  out[3] = R[0]*fx + R[3]*fy + R[6]*fz;
  out[4] = R[1]*fx + R[4]*fy + R[7]*fz;
  out[5] = R[2]*fx + R[5]*fy + R[8]*fz;
}

// 8 lanes per element. Roles sub=0..6: mass-matrix column j=sub (dq=0, ddq=e_j,
// g=0, ftip=0). Role sub=7: bias torque h (real dq, ddq=0, real g, ftip).
extern "C" __global__ void __launch_bounds__(64, 2)
arm_kernel(const float* __restrict__ state, const float* __restrict__ torque,
           const float* __restrict__ Mp, const float* __restrict__ Ain,
           const float* __restrict__ Gp, const float* __restrict__ grav,
           const float* __restrict__ ftip_in, float* __restrict__ out)
{
  __shared__ SConsts C;
  __shared__ float XL[8][100];  // per element: 7 joints x (R 9 + p 3); stride 100 dwords
  __shared__ float CL[8][68];   // per element: column gather, CL[e][k*8+sub]
  const int t = threadIdx.x;

  // Cooperative constant staging.
  {
    int i = t >> 3;
    #pragma unroll
    for (int kk = (t & 7); kk < 12; kk += 8) {
      if (kk < 9) {
        int r = kk / 3, c = kk - 3*(kk/3);
        C.MrT[i][c*3 + r] = Mp[i*16 + r*4 + c];
      } else {
        int r = kk - 9;
        C.mp[i][r] = Mp[i*16 + r*4 + 3];
      }
    }
    if (t < 42) {
      int i2 = t / 6, k = t - 6*(t/6);
      C.A[i2][k] = Ain[t];
      C.Gd[i2][k] = (k < 3) ? Gp[i2*4 + k] : Gp[i2*4 + 3];
    }
    if (t < 3) C.g[t] = grav[t];
    if (t < 6) C.ftip[t] = ftip_in[t];
  }
  syncw();
  if (t < 3)
    C.X7p[t] = -(C.MrT[7][t*3+0]*C.mp[7][0] + C.MrT[7][t*3+1]*C.mp[7][1] + C.MrT[7][t*3+2]*C.mp[7][2]);
  syncw();

  const int sub = t & 7;
  const int e   = t >> 3;
  const int b   = blockIdx.x * 8 + e;
  const int subc = (sub < 7) ? sub : 6;   // clamp so lane 7's scalar loads stay in-bounds

  float dq0[7], tau[7], dqs[7];
  #pragma unroll
  for (int k = 0; k < 7; ++k) {
    dq0[k] = state[b*14 + 7 + k];
    tau[k] = torque[b*7 + k] * 50.0f;
    dqs[k] = dq0[k];
  }
  float q0s  = state[b*14 + subc];   // this lane's own joint q
  float dq0s = dq0[0];
  #pragma unroll
  for (int k = 1; k < 7; ++k) dq0s = (subc == k) ? dq0[k] : dq0s;

  float qss = q0s, dqss = dq0s;       // this lane's own qs/dqs
  float accqs = 0.0f, accdqs = 0.0f;  // RK4 accumulators for own joint
  float a[7];
  const float gm = (sub == 7) ? 1.0f : 0.0f;

  #pragma unroll 1
  for (int stage = 0; stage < 4; ++stage) {
    syncw();   // XL safe to overwrite (same-wave DS order)
    if (sub < 7) {
      float Re[9], pe[3];
      exp6_dev(-C.A[sub][0]*qss, -C.A[sub][1]*qss, -C.A[sub][2]*qss,
               -C.A[sub][3]*qss, -C.A[sub][4]*qss, -C.A[sub][5]*qss, Re, pe);
      float Xr[12];
      #pragma unroll
      for (int r = 0; r < 3; ++r) {
        #pragma unroll
        for (int c = 0; c < 3; ++c)
          Xr[r*3+c] = Re[r*3+0]*C.MrT[sub][0+c] + Re[r*3+1]*C.MrT[sub][3+c] + Re[r*3+2]*C.MrT[sub][6+c];
      }
      #pragma unroll
      for (int r = 0; r < 3; ++r)
        Xr[9+r] = pe[r] - (Xr[r*3+0]*C.mp[sub][0] + Xr[r*3+1]*C.mp[sub][1] + Xr[r*3+2]*C.mp[sub][2]);
      float4* dst = (float4*)&XL[e][sub*12];
      dst[0] = make_float4(Xr[0],Xr[1],Xr[2],Xr[3]);
      dst[1] = make_float4(Xr[4],Xr[5],Xr[6],Xr[7]);
      dst[2] = make_float4(Xr[8],Xr[9],Xr[10],Xr[11]);
    }
    syncw();

    // Hoist all 7 joint transforms into registers once; reuse in fwd + bwd.
    float X[7][12];
    #pragma unroll
    for (int i = 0; i < 7; ++i) {
      const float4* sx = (const float4*)&XL[e][i*12];
      float4 x0 = sx[0], x1 = sx[1], x2 = sx[2];
      X[i][0]=x0.x; X[i][1]=x0.y; X[i][2]=x0.z; X[i][3]=x0.w;
      X[i][4]=x1.x; X[i][5]=x1.y; X[i][6]=x1.z; X[i][7]=x1.w;
      X[i][8]=x2.x; X[i][9]=x2.y; X[i][10]=x2.z; X[i][11]=x2.w;
    }

    // ---- generalized RNEA (per-role dq/ddq/g/ftip) ----
    float V[6] = {0,0,0,0,0,0};
    float Vd[6];
    Vd[0]=0.0f; Vd[1]=0.0f; Vd[2]=0.0f;
    Vd[3] = -gm*C.g[0]; Vd[4] = -gm*C.g[1]; Vd[5] = -gm*C.g[2];
    float Fb[7][6];
    #pragma unroll
    for (int i = 0; i < 7; ++i) {
      float dqi  = (sub == 7) ? dqs[i] : 0.0f;
      float ddqi = (sub == i) ? 1.0f : 0.0f;
      float tv[6];
      Xapply(X[i], X[i]+9, V, tv);
      #pragma unroll
      for (int k = 0; k < 6; ++k) V[k] = tv[k] + C.A[i][k]*dqi;
      Xapply(X[i], X[i]+9, Vd, tv);
      float wx=V[0],wy=V[1],wz=V[2],vx=V[3],vy=V[4],vz=V[5];
      float ax=C.A[i][0],ay=C.A[i][1],az=C.A[i][2];
      float bx=C.A[i][3],by=C.A[i][4],bz=C.A[i][5];
      Vd[0] = tv[0] + ax*ddqi + (wy*az - wz*ay)*dqi;
      Vd[1] = tv[1] + ay*ddqi + (wz*ax - wx*az)*dqi;
      Vd[2] = tv[2] + az*ddqi + (wx*ay - wy*ax)*dqi;
      Vd[3] = tv[3] + bx*ddqi + (vy*az - vz*ay + wy*bz - wz*by)*dqi;
      Vd[4] = tv[4] + by*ddqi + (vz*ax - vx*az + wz*bx - wx*bz)*dqi;
      Vd[5] = tv[5] + bz*ddqi + (vx*ay - vy*ax + wx*by - wy*bx)*dqi;
      float g0=C.Gd[i][0], g1=C.Gd[i][1], g2=C.Gd[i][2], m=C.Gd[i][3];
      float Gt0=g0*wx, Gt1=g1*wy, Gt2=g2*wz;
      float Gb0=m*vx,  Gb1=m*vy,  Gb2=m*vz;
      Fb[i][0] = g0*Vd[0] + (wy*Gt2 - wz*Gt1) + (vy*Gb2 - vz*Gb1);
      Fb[i][1] = g1*Vd[1] + (wz*Gt0 - wx*Gt2) + (vz*Gb0 - vx*Gb2);
      Fb[i][2] = g2*Vd[2] + (wx*Gt1 - wy*Gt0) + (vx*Gb1 - vy*Gb0);
      Fb[i][3] = m*Vd[3] + (wy*Gb2 - wz*Gb1);
      Fb[i][4] = m*Vd[4] + (wz*Gb0 - wx*Gb2);
      Fb[i][5] = m*Vd[5] + (wx*Gb1 - wy*Gb0);
    }
    float col[7];
    float F[6];
    #pragma unroll
    for (int k = 0; k < 6; ++k) F[k] = gm*C.ftip[k];
    #pragma unroll
    for (int i = 6; i >= 0; --i) {
      float tv[6];
      if (i == 6) XTapply(C.MrT[7], C.X7p, F, tv);
      else        XTapply(X[i+1], X[i+1]+9, F, tv);
      #pragma unroll
      for (int k = 0; k < 6; ++k) F[k] = tv[k] + Fb[i][k];
      col[i] = dot6(F, C.A[i]);
    }

    // ---- gather full M + rhs via LDS (same-wave DS order; no barriers) ----
    syncw();
    #pragma unroll
    for (int k = 0; k < 7; ++k) CL[e][k*8 + sub] = col[k];
    syncw();
    float Mm[7][7], rhs[7];
    #pragma unroll
    for (int i = 0; i < 7; ++i) {
      const float4* rp = (const float4*)&CL[e][i*8];
      float4 r0 = rp[0], r1 = rp[1];
      Mm[i][0]=r0.x; Mm[i][1]=r0.y; Mm[i][2]=r0.z; Mm[i][3]=r0.w;
      Mm[i][4]=r1.x; Mm[i][5]=r1.y; Mm[i][6]=r1.z;
      rhs[i] = tau[i] - r1.w;
    }

    // ---- solve M a = rhs (SPD, no pivot); pivot reciprocals via v_rcp ----
    float invd[7];
    #pragma unroll
    for (int k = 0; k < 7; ++k) {
      invd[k] = __builtin_amdgcn_rcpf(Mm[k][k]);
      #pragma unroll
      for (int i2 = k+1; i2 < 7; ++i2) {
        float f = Mm[i2][k] * invd[k];
        #pragma unroll
        for (int c2 = k+1; c2 < 7; ++c2) Mm[i2][c2] -= f * Mm[k][c2];
        rhs[i2] -= f * rhs[k];
      }
    }
    #pragma unroll
    for (int i2 = 6; i2 >= 0; --i2) {
      float s = rhs[i2];
      #pragma unroll
      for (int c2 = i2+1; c2 < 7; ++c2) s -= Mm[i2][c2] * a[c2];
      a[i2] = s * invd[i2];
    }

    // ---- RK4 accumulate / advance (own-joint scalars only) ----
    float a_own = a[0];
    #pragma unroll
    for (int k = 1; k < 7; ++k) a_own = (subc == k) ? a[k] : a_own;
    float w = (stage == 1 || stage == 2) ? 2.0f : 1.0f;
    accqs  += w*dqss;
    accdqs += w*a_own;
    if (stage < 3) {
      float cc = (stage == 2) ? 0.1f : 0.05f;
      qss  = q0s + cc*dqss;       // uses pre-update dqss (stage input)
      dqss = dq0s + cc*a_own;
      #pragma unroll
      for (int k = 0; k < 7; ++k) dqs[k] = dq0[k] + cc*a[k];
    }
  }

  const float c6 = (float)(0.1/6.0);
  const float PI_F = 3.14159265358979323846f;
  const float TWO_PI_F = 6.28318530717958647692f;
  const float INV_TWO_PI_F = 0.15915494309189535f;
  float q1 = q0s  + c6*accqs;
  float d1 = dq0s + c6*accdqs;
  float x = q1 + PI_F;
  float n = floorf(x * INV_TWO_PI_F);
  float y = fmaf(n, -TWO_PI_F, x);
  y = (y < 0.0f) ? y + TWO_PI_F : y;
  y = (y >= TWO_PI_F) ? y - TWO_PI_F : y;
  float qw_own  = y - PI_F;
  float dqw_own = fminf(fmaxf(d1, -20.0f), 20.0f);
  if (sub < 7) {
    out[b*14 + sub]     = qw_own;
    out[b*14 + 7 + sub] = dqw_own;
  }

  // ---- FK: lane sub<7 builds its link transform L_sub = M_sub * exp6(A q);
  //      ee = L0·(L1·(...(L6·mp7))) needs only translations. ----
  syncw();   // XL safe to overwrite
  if (sub < 7) {
    float Re[9], pe[3];
    exp6_dev(C.A[sub][0]*qw_own, C.A[sub][1]*qw_own, C.A[sub][2]*qw_own,
             C.A[sub][3]*qw_own, C.A[sub][4]*qw_own, C.A[sub][5]*qw_own, Re, pe);
    float L[12];
    #pragma unroll
    for (int r = 0; r < 3; ++r) {
      #pragma unroll
      for (int c = 0; c < 3; ++c)   // Mr[r][k] = MrT[k*3+r]
        L[r*3+c] = C.MrT[sub][0*3+r]*Re[0*3+c] + C.MrT[sub][1*3+r]*Re[1*3+c] + C.MrT[sub][2*3+r]*Re[2*3+c];
      L[9+r] = C.MrT[sub][0*3+r]*pe[0] + C.MrT[sub][1*3+r]*pe[1] + C.MrT[sub][2*3+r]*pe[2] + C.mp[sub][r];
    }
    float4* dst = (float4*)&XL[e][sub*12];
    dst[0] = make_float4(L[0],L[1],L[2],L[3]);
    dst[1] = make_float4(L[4],L[5],L[6],L[7]);
    dst[2] = make_float4(L[8],L[9],L[10],L[11]);
  }
  syncw();
  // Prefetch all links into registers, then run the 84-FMA translation chain.
  float X2[7][12];
  #pragma unroll
  for (int i = 0; i < 7; ++i) {
    const float4* sx = (const float4*)&XL[e][i*12];
    float4 x0 = sx[0], x1 = sx[1], x2 = sx[2];
    X2[i][0]=x0.x; X2[i][1]=x0.y; X2[i][2]=x0.z; X2[i][3]=x0.w;
    X2[i][4]=x1.x; X2[i][5]=x1.y; X2[i][6]=x1.z; X2[i][7]=x1.w;
    X2[i][8]=x2.x; X2[i][9]=x2.y; X2[i][10]=x2.z; X2[i][11]=x2.w;
  }
  float v0 = C.mp[7][0], v1 = C.mp[7][1], v2 = C.mp[7][2];
  #pragma unroll
  for (int i = 6; i >= 0; --i) {
    float n0 = X2[i][0]*v0 + X2[i][1]*v1 + X2[i][2]*v2 + X2[i][9];
    float n1 = X2[i][3]*v0 + X2[i][4]*v1 + X2[i][5]*v2 + X2[i][10];
    float n2 = X2[i][6]*v0 + X2[i][7]*v1 + X2[i][8]*v2 + X2[i][11];
    v0 = n0; v1 = n1; v2 = n2;
  }
  {
    float ev = v0;
    ev = (sub == 1) ? v1 : ev;
    ev = (sub == 2) ? v2 : ev;
    if (sub < 3) out[NB*14 + b*3 + sub] = ev;
  }
}

extern "C" void kernel_launch(void* const* d_in, const int* in_sizes, int n_in,
                              void* d_out, int out_size, void* d_ws, size_t ws_size,
                              hipStream_t stream) {
  const float* state  = (const float*)d_in[0];
  const float* torque = (const float*)d_in[1];
  const float* Mp     = (const float*)d_in[2];
  const float* Ain    = (const float*)d_in[3];
  const float* Gp     = (const float*)d_in[4];
  const float* grav   = (const float*)d_in[5];
  const float* ftip   = (const float*)d_in[6];
  float* out = (float*)d_out;
  hipLaunchKernelGGL(arm_kernel, dim3(NB/8), dim3(64), 0, stream,
                     state, torque, Mp, Ain, Gp, grav, ftip, out);
}